// Round 2
// baseline (774.405 us; speedup 1.0000x reference)
//
#include <hip/hip_runtime.h>
#include <hip/hip_bf16.h>
#include <stdint.h>

typedef unsigned short ushort_t;
typedef unsigned int uint_t;

// Problem sizes (fixed by reference)
#define BB 16
#define TT 2048
#define DD 1024
#define HH 1024
#define MM (BB * TT)   // 32768
#define NN (3 * HH)    // 3072
#define KK DD          // 1024
#define NCHUNK 32
#define CLEN (TT / NCHUNK)  // 64

typedef __bf16 bf16x8 __attribute__((ext_vector_type(8)));
typedef __bf16 bf16x4 __attribute__((ext_vector_type(4)));
typedef float floatx4 __attribute__((ext_vector_type(4)));

// ---------- helpers ----------
__device__ __forceinline__ ushort_t f2b(float f) {
  union { float f; uint_t u; } v; v.f = f;
  uint_t u = v.u;
  uint_t r = (u + 0x7FFFu + ((u >> 16) & 1u)) >> 16;  // RNE
  return (ushort_t)r;
}
__device__ __forceinline__ float b2f_lo(uint_t u) {
  union { uint_t u; float f; } v; v.u = u << 16; return v.f;
}
__device__ __forceinline__ float b2f_hi(uint_t u) {
  union { uint_t u; float f; } v; v.u = u & 0xFFFF0000u; return v.f;
}
__device__ __forceinline__ float fast_sigmoid(float x) {
  return 1.0f / (1.0f + __expf(-x));
}
__device__ __forceinline__ float fast_tanh(float x) {
  x = fminf(fmaxf(x, -15.0f), 15.0f);
  float e = __expf(2.0f * x);
  return (e - 1.0f) / (e + 1.0f);
}

// async global->LDS, 16B per lane, dst = wave-uniform base + lane*16
__device__ __forceinline__ void async_ld16(const void* g, void* l) {
  auto gp = (const __attribute__((address_space(1))) unsigned int*)(uintptr_t)g;
  unsigned loff = (unsigned)(uintptr_t)l;
  auto lp = (__attribute__((address_space(3))) unsigned int*)loff;
  __builtin_amdgcn_global_load_lds(gp, lp, 16, 0, 0);
}

// ---------- kernel 1: W [K][N] fp32 -> Wt [N][K] bf16 ----------
__global__ __launch_bounds__(256) void transW_kernel(const float* __restrict__ W,
                                                     ushort_t* __restrict__ Wt) {
  __shared__ ushort_t tile[32][33];
  int tx = threadIdx.x;  // 0..31
  int ty = threadIdx.y;  // 0..7
  int n0 = blockIdx.x * 32;
  int k0 = blockIdx.y * 32;
#pragma unroll
  for (int r = 0; r < 4; r++) {
    int k = k0 + ty + r * 8;
    tile[ty + r * 8][tx] = f2b(W[(size_t)k * NN + n0 + tx]);
  }
  __syncthreads();
#pragma unroll
  for (int r = 0; r < 4; r++) {
    int n = n0 + ty + r * 8;
    Wt[(size_t)n * KK + k0 + tx] = tile[tx][ty + r * 8];
  }
}

// ---------- kernel 2: GEMM U_T[g][h][m] = (x @ W + b), sigmoid on f/r gates ----------
// A: x fp32 [M][K] (converted to bf16 inline), Bt: Wt [N][K] bf16.
// 128x128 tile, BK=32, 4 waves 2x2. Output transposed per gate plane.
__global__ __launch_bounds__(256) void gemm_kernel(const float* __restrict__ x,
                                                   const ushort_t* __restrict__ Btb,
                                                   const float* __restrict__ bias,
                                                   ushort_t* __restrict__ U) {
  __shared__ __align__(16) ushort_t As[128 * 32];
  __shared__ __align__(16) ushort_t Bs[128 * 32];
  const int tid = threadIdx.x;
  const int lane = tid & 63;
  const int wave = tid >> 6;
  const int wm = wave >> 1, wn = wave & 1;
  const int bn = blockIdx.x, bm = blockIdx.y;
  const int rowA0 = bm * 128, rowB0 = bn * 128;

  // B staging via async global->LDS (bf16), wave fills rows [32w, 32w+32)
  const int srow = wave * 32 + (lane >> 2);
  const int schunk = (lane & 3) * 8;  // ushort offset (16B chunks)
  const ushort_t* gB = Btb + (size_t)(rowB0 + srow) * KK + schunk;
  ushort_t* lB = Bs + wave * 32 * 32;  // wave-uniform base; HW adds lane*16B

  // A staging via register path: fp32 load -> bf16 cvt -> ds_write_b128
  // same tile geometry; two halves of 16 rows
  const float* gA0 = x + (size_t)(rowA0 + srow) * KK + schunk;
  const float* gA1 = gA0 + (size_t)16 * KK;
  ushort_t* lA0 = As + srow * 32 + schunk;
  ushort_t* lA1 = lA0 + 16 * 32;

  floatx4 acc[4][4];
#pragma unroll
  for (int i = 0; i < 4; i++)
#pragma unroll
    for (int j = 0; j < 4; j++) acc[i][j] = (floatx4){0.f, 0.f, 0.f, 0.f};

  const int m16 = lane & 15;
  const int q8 = (lane >> 4) * 8;
  const ushort_t* rA = As + (wm * 64 + m16) * 32 + q8;
  const ushort_t* rB = Bs + (wn * 64 + m16) * 32 + q8;

  for (int k0 = 0; k0 < KK; k0 += 32) {
    __syncthreads();
    async_ld16(gB + k0, lB);
    async_ld16(gB + 16 * KK + k0, lB + 16 * 32);
    {
      float4 a0 = *(const float4*)(gA0 + k0);
      float4 a1 = *(const float4*)(gA0 + k0 + 4);
      float4 a2 = *(const float4*)(gA1 + k0);
      float4 a3 = *(const float4*)(gA1 + k0 + 4);
      bf16x8 w0, w1;
      w0[0] = (__bf16)a0.x; w0[1] = (__bf16)a0.y; w0[2] = (__bf16)a0.z; w0[3] = (__bf16)a0.w;
      w0[4] = (__bf16)a1.x; w0[5] = (__bf16)a1.y; w0[6] = (__bf16)a1.z; w0[7] = (__bf16)a1.w;
      w1[0] = (__bf16)a2.x; w1[1] = (__bf16)a2.y; w1[2] = (__bf16)a2.z; w1[3] = (__bf16)a2.w;
      w1[4] = (__bf16)a3.x; w1[5] = (__bf16)a3.y; w1[6] = (__bf16)a3.z; w1[7] = (__bf16)a3.w;
      *(bf16x8*)lA0 = w0;
      *(bf16x8*)lA1 = w1;
    }
    __syncthreads();
    bf16x8 af[4], bfr[4];
#pragma unroll
    for (int i = 0; i < 4; i++) af[i] = *(const bf16x8*)(rA + i * 16 * 32);
#pragma unroll
    for (int j = 0; j < 4; j++) bfr[j] = *(const bf16x8*)(rB + j * 16 * 32);
#pragma unroll
    for (int i = 0; i < 4; i++)
#pragma unroll
      for (int j = 0; j < 4; j++)
        acc[i][j] = __builtin_amdgcn_mfma_f32_16x16x32_bf16(af[i], bfr[j], acc[i][j], 0, 0, 0);
  }

  // epilogue: C/D layout col = lane&15, row(m) = (lane>>4)*4 + reg.
  // U_T plane layout: U[g][h][m] -> lane's 4 regs are 4 consecutive m -> 8B store.
  const int g = bn >> 3;  // 0: x_tilde, 1: f, 2: r
  const int q4 = (lane >> 4) * 4;
  ushort_t* plane = U + (size_t)g * HH * MM;
  const int hbase = (bn & 7) * 128 + wn * 64;
  const int mbase = rowA0 + wm * 64 + q4;
#pragma unroll
  for (int j = 0; j < 4; j++) {
    int colh = hbase + j * 16 + m16;
    float bv = bias[rowB0 + wn * 64 + j * 16 + m16];
    ushort_t* pcol = plane + (size_t)colh * MM + mbase;
#pragma unroll
    for (int i = 0; i < 4; i++) {
      float v0 = acc[i][j][0] + bv;
      float v1 = acc[i][j][1] + bv;
      float v2 = acc[i][j][2] + bv;
      float v3 = acc[i][j][3] + bv;
      if (g != 0) {
        v0 = fast_sigmoid(v0); v1 = fast_sigmoid(v1);
        v2 = fast_sigmoid(v2); v3 = fast_sigmoid(v3);
      }
      bf16x4 pk;
      pk[0] = (__bf16)v0; pk[1] = (__bf16)v1; pk[2] = (__bf16)v2; pk[3] = (__bf16)v3;
      *(bf16x4*)(pcol + i * 16) = pk;
    }
  }
}

// ---------- kernel 3: per-chunk scan summaries (A = prod f, B = local c end) ----------
// U_T layout: per-thread reads are contiguous 128B per gate plane.
__global__ __launch_bounds__(256) void pass1_kernel(const ushort_t* __restrict__ U,
                                                    float* __restrict__ Asum,
                                                    float* __restrict__ Bsum) {
  int gid = blockIdx.x * 256 + threadIdx.x;  // 524288 threads
  int chunk = gid & 31;
  int h = (gid >> 5) & 1023;
  int b = gid >> 15;
  size_t base = (size_t)h * MM + b * TT + chunk * CLEN;
  const uint4* pX = (const uint4*)(U + base);
  const uint4* pF = (const uint4*)(U + (size_t)HH * MM + base);
  float c = 0.f, A = 1.f;
#pragma unroll
  for (int v = 0; v < 8; v++) {
    uint4 xv = pX[v];
    uint4 fv = pF[v];
    const uint_t* xw = (const uint_t*)&xv;
    const uint_t* fw = (const uint_t*)&fv;
#pragma unroll
    for (int w = 0; w < 4; w++) {
      float x0 = b2f_lo(xw[w]), x1 = b2f_hi(xw[w]);
      float f0 = b2f_lo(fw[w]), f1 = b2f_hi(fw[w]);
      A *= f0; c = f0 * c + (1.f - f0) * x0;
      A *= f1; c = f1 * c + (1.f - f1) * x1;
    }
  }
  size_t sidx = ((size_t)(b * 1024 + h)) * NCHUNK + chunk;
  Asum[sidx] = A;
  Bsum[sidx] = c;
}

// ---------- kernel 4: sequential combine over chunk summaries ----------
__global__ __launch_bounds__(256) void fixup_kernel(const float* __restrict__ Asum,
                                                    const float* __restrict__ Bsum,
                                                    float* __restrict__ Cinit) {
  int gid = blockIdx.x * 256 + threadIdx.x;  // 16384
  int h = gid & 1023;
  int b = gid >> 10;
  size_t base = ((size_t)(b * 1024 + h)) * NCHUNK;
  const float4* pa = (const float4*)(Asum + base);
  const float4* pb = (const float4*)(Bsum + base);
  float4 av[8], bv[8], cv[8];
#pragma unroll
  for (int v = 0; v < 8; v++) { av[v] = pa[v]; bv[v] = pb[v]; }
  float c = 0.f;
  const float* af = (const float*)av;
  const float* bf = (const float*)bv;
  float* cf = (float*)cv;
#pragma unroll
  for (int j = 0; j < NCHUNK; j++) {
    cf[j] = c;
    c = bf[j] + af[j] * c;
  }
  float4* pc = (float4*)(Cinit + base);
#pragma unroll
  for (int v = 0; v < 8; v++) pc[v] = cv[v];
}

// ---------- kernel 5: final scan producing h (out [B,T,H] fp32) ----------
__global__ __launch_bounds__(256) void pass3_kernel(const ushort_t* __restrict__ U,
                                                    const float* __restrict__ Cinit,
                                                    float* __restrict__ out) {
  int gid = blockIdx.x * 256 + threadIdx.x;  // 524288
  int h = gid & 1023;            // lane-major h -> coalesced out writes
  int chunk = (gid >> 10) & 31;
  int b = gid >> 15;
  size_t base = (size_t)h * MM + b * TT + chunk * CLEN;
  const uint4* pX = (const uint4*)(U + base);
  const uint4* pF = (const uint4*)(U + (size_t)HH * MM + base);
  const uint4* pR = (const uint4*)(U + 2 * (size_t)HH * MM + base);
  float c = Cinit[((size_t)(b * 1024 + h)) * NCHUNK + chunk];
  float* orow = out + ((size_t)(b * TT + chunk * CLEN)) * HH + h;
#pragma unroll
  for (int v = 0; v < 8; v++) {
    uint4 xv = pX[v];
    uint4 fv = pF[v];
    uint4 rv = pR[v];
    const uint_t* xw = (const uint_t*)&xv;
    const uint_t* fw = (const uint_t*)&fv;
    const uint_t* rw = (const uint_t*)&rv;
#pragma unroll
    for (int w = 0; w < 4; w++) {
      float x0 = b2f_lo(xw[w]), x1 = b2f_hi(xw[w]);
      float f0 = b2f_lo(fw[w]), f1 = b2f_hi(fw[w]);
      float r0 = b2f_lo(rw[w]), r1 = b2f_hi(rw[w]);
      c = f0 * c + (1.f - f0) * x0;
      float h0 = r0 * fast_tanh(c) + (1.f - r0) * x0;
      c = f1 * c + (1.f - f1) * x1;
      float h1 = r1 * fast_tanh(c) + (1.f - r1) * x1;
      int t = v * 8 + w * 2;
      orow[(size_t)t * HH] = h0;
      orow[(size_t)(t + 1) * HH] = h1;
    }
  }
}

extern "C" void kernel_launch(void* const* d_in, const int* in_sizes, int n_in,
                              void* d_out, int out_size, void* d_ws, size_t ws_size,
                              hipStream_t stream) {
  (void)in_sizes; (void)n_in; (void)out_size; (void)ws_size;
  const float* x = (const float*)d_in[0];
  const float* W = (const float*)d_in[1];
  const float* bias = (const float*)d_in[2];
  float* out = (float*)d_out;
  char* ws = (char*)d_ws;

  // workspace layout (~214 MB)
  ushort_t* Wt  = (ushort_t*)ws;                          //   6,291,456 B
  ushort_t* U   = (ushort_t*)(ws + 6291456ull);           // 201,326,592 B  (U_T [3][H][M])
  float* Asum   = (float*)(ws + 207618048ull);            //   2,097,152 B
  float* Bsum   = (float*)(ws + 209715200ull);            //   2,097,152 B
  float* Cinit  = (float*)(ws + 211812352ull);            //   2,097,152 B

  transW_kernel<<<dim3(NN / 32, KK / 32), dim3(32, 8), 0, stream>>>(W, Wt);
  gemm_kernel<<<dim3(NN / 128, MM / 128), 256, 0, stream>>>(x, Wt, bias, U);
  pass1_kernel<<<2048, 256, 0, stream>>>(U, Asum, Bsum);
  fixup_kernel<<<64, 256, 0, stream>>>(Asum, Bsum, Cinit);
  pass3_kernel<<<2048, 256, 0, stream>>>(U, Cinit, out);
}

// Round 3
// 583.110 us; speedup vs baseline: 1.3281x; 1.3281x over previous
//
#include <hip/hip_runtime.h>
#include <hip/hip_bf16.h>
#include <stdint.h>

typedef unsigned short ushort_t;
typedef unsigned int uint_t;

// Problem sizes (fixed by reference)
#define BB 16
#define TT 2048
#define DD 1024
#define HH 1024
#define MM (BB * TT)   // 32768
#define NN (3 * HH)    // 3072
#define KK DD          // 1024
#define NCHUNK 64
#define CLEN (TT / NCHUNK)  // 32
#define PLANE ((size_t)HH * MM)

typedef __bf16 bf16x8 __attribute__((ext_vector_type(8)));
typedef float floatx4 __attribute__((ext_vector_type(4)));

// ---------- helpers ----------
__device__ __forceinline__ ushort_t f2b(float f) {
  union { float f; uint_t u; } v; v.f = f;
  uint_t u = v.u;
  uint_t r = (u + 0x7FFFu + ((u >> 16) & 1u)) >> 16;  // RNE
  return (ushort_t)r;
}
__device__ __forceinline__ float b2f_lo(uint_t u) {
  union { uint_t u; float f; } v; v.u = u << 16; return v.f;
}
__device__ __forceinline__ float b2f_hi(uint_t u) {
  union { uint_t u; float f; } v; v.u = u & 0xFFFF0000u; return v.f;
}
__device__ __forceinline__ float fast_sigmoid(float x) {
  return 1.0f / (1.0f + __expf(-x));
}
__device__ __forceinline__ float fast_tanh(float x) {
  x = fminf(fmaxf(x, -15.0f), 15.0f);
  float e = __expf(2.0f * x);
  return (e - 1.0f) / (e + 1.0f);
}

// async global->LDS, 16B per lane, dst = wave-uniform base + lane*16
__device__ __forceinline__ void async_ld16(const void* g, void* l) {
  auto gp = (const __attribute__((address_space(1))) unsigned int*)(uintptr_t)g;
  unsigned loff = (unsigned)(uintptr_t)l;
  auto lp = (__attribute__((address_space(3))) unsigned int*)loff;
  __builtin_amdgcn_global_load_lds(gp, lp, 16, 0, 0);
}

// ---------- kernel 0: x fp32 -> bf16 ----------
__global__ __launch_bounds__(256) void cvt_x_kernel(const float4* __restrict__ x,
                                                    ushort4* __restrict__ o, int n4) {
  int stride = gridDim.x * blockDim.x;
  for (int i = blockIdx.x * blockDim.x + threadIdx.x; i < n4; i += stride) {
    float4 v = x[i];
    o[i] = make_ushort4(f2b(v.x), f2b(v.y), f2b(v.z), f2b(v.w));
  }
}

// ---------- kernel 1: W [K][N] fp32 -> Wt [N][K] bf16 ----------
__global__ __launch_bounds__(256) void transW_kernel(const float* __restrict__ W,
                                                     ushort_t* __restrict__ Wt) {
  __shared__ ushort_t tile[32][33];
  int tx = threadIdx.x;  // 0..31
  int ty = threadIdx.y;  // 0..7
  int n0 = blockIdx.x * 32;
  int k0 = blockIdx.y * 32;
#pragma unroll
  for (int r = 0; r < 4; r++) {
    int k = k0 + ty + r * 8;
    tile[ty + r * 8][tx] = f2b(W[(size_t)k * NN + n0 + tx]);
  }
  __syncthreads();
#pragma unroll
  for (int r = 0; r < 4; r++) {
    int n = n0 + ty + r * 8;
    Wt[(size_t)n * KK + k0 + tx] = tile[tx][ty + r * 8];
  }
}

// ---------- kernel 2: GEMM, output planar time-major U[g][m][h] bf16 ----------
// A: x_bf [M][K] bf16, Bt: Wt [N][K] bf16. 128x128 tile, BK=32, 4 waves 2x2.
// Epilogue transposes through LDS so stores are h-contiguous 16B/lane.
__global__ __launch_bounds__(256) void gemm_kernel(const ushort_t* __restrict__ Abf,
                                                   const ushort_t* __restrict__ Btb,
                                                   const float* __restrict__ bias,
                                                   ushort_t* __restrict__ U) {
  // staging needs 2*128*32 = 8192 elems (16KB); transpose needs 64*132 = 8448
  __shared__ __align__(16) ushort_t smem[8448];
  ushort_t* As = smem;
  ushort_t* Bs = smem + 4096;
  const int tid = threadIdx.x;
  const int lane = tid & 63;
  const int wave = tid >> 6;
  const int wm = wave >> 1, wn = wave & 1;
  const int bn = blockIdx.x, bm = blockIdx.y;
  const int rowA0 = bm * 128, rowB0 = bn * 128;

  // staging: wave w fills rows [32w, 32w+32); lane -> (row, 16B chunk)
  const int srow = wave * 32 + (lane >> 2);
  const int schunk = (lane & 3) * 8;  // ushort offset
  const ushort_t* gA = Abf + (size_t)(rowA0 + srow) * KK + schunk;
  const ushort_t* gB = Btb + (size_t)(rowB0 + srow) * KK + schunk;
  ushort_t* lA = As + wave * 32 * 32;  // wave-uniform; HW adds lane*16B
  ushort_t* lB = Bs + wave * 32 * 32;

  floatx4 acc[4][4];
#pragma unroll
  for (int i = 0; i < 4; i++)
#pragma unroll
    for (int j = 0; j < 4; j++) acc[i][j] = (floatx4){0.f, 0.f, 0.f, 0.f};

  const int m16 = lane & 15;
  const int q8 = (lane >> 4) * 8;
  const int q4 = (lane >> 4) * 4;
  const ushort_t* rA = As + (wm * 64 + m16) * 32 + q8;
  const ushort_t* rB = Bs + (wn * 64 + m16) * 32 + q8;

  for (int k0 = 0; k0 < KK; k0 += 32) {
    __syncthreads();
    async_ld16(gA + k0, lA);
    async_ld16(gA + 16 * KK + k0, lA + 16 * 32);
    async_ld16(gB + k0, lB);
    async_ld16(gB + 16 * KK + k0, lB + 16 * 32);
    __syncthreads();
    bf16x8 af[4], bfr[4];
#pragma unroll
    for (int i = 0; i < 4; i++) af[i] = *(const bf16x8*)(rA + i * 16 * 32);
#pragma unroll
    for (int j = 0; j < 4; j++) bfr[j] = *(const bf16x8*)(rB + j * 16 * 32);
#pragma unroll
    for (int i = 0; i < 4; i++)
#pragma unroll
      for (int j = 0; j < 4; j++)
        acc[i][j] = __builtin_amdgcn_mfma_f32_16x16x32_bf16(af[i], bfr[j], acc[i][j], 0, 0, 0);
  }

  // ---- epilogue: bias + sigmoid, LDS transpose, coalesced h-contiguous stores ----
  const int g = bn >> 3;  // 0: x_tilde, 1: f, 2: r
  ushort_t* plane = U + (size_t)g * PLANE;
  const int hbase = (bn & 7) * 128;

  __syncthreads();  // everyone done reading As/Bs before aliasing as tr
  ushort_t* tr = smem;  // [64][132] padded rows
#pragma unroll
  for (int hm = 0; hm < 2; hm++) {
    if (wm == hm) {
#pragma unroll
      for (int j = 0; j < 4; j++) {
        int hl = wn * 64 + j * 16 + m16;        // 0..127
        float bv = bias[rowB0 + hl];
#pragma unroll
        for (int i = 0; i < 4; i++) {
          float v0 = acc[i][j][0] + bv;
          float v1 = acc[i][j][1] + bv;
          float v2 = acc[i][j][2] + bv;
          float v3 = acc[i][j][3] + bv;
          if (g != 0) {
            v0 = fast_sigmoid(v0); v1 = fast_sigmoid(v1);
            v2 = fast_sigmoid(v2); v3 = fast_sigmoid(v3);
          }
          int ml = i * 16 + q4;                  // 0..60
          tr[(ml + 0) * 132 + hl] = f2b(v0);
          tr[(ml + 1) * 132 + hl] = f2b(v1);
          tr[(ml + 2) * 132 + hl] = f2b(v2);
          tr[(ml + 3) * 132 + hl] = f2b(v3);
        }
      }
    }
    __syncthreads();
#pragma unroll
    for (int it = 0; it < 4; it++) {
      int idx = it * 256 + tid;    // 0..1023
      int row = idx >> 4;          // 0..63
      int c = idx & 15;            // 8 h each
      bf16x8 v = *(const bf16x8*)(tr + row * 132 + c * 8);
      *(bf16x8*)(plane + (size_t)(rowA0 + hm * 64 + row) * HH + hbase + c * 8) = v;
    }
    __syncthreads();
  }
}

// ---------- kernel 3: per-chunk scan summaries (A = prod f, B = local c end) ----------
// U planar [g][m][h]; lanes take consecutive h-pairs -> 512B/wave coalesced.
__global__ __launch_bounds__(256) void pass1_kernel(const ushort_t* __restrict__ U,
                                                    float* __restrict__ Asum,
                                                    float* __restrict__ Bsum) {
  int gid = blockIdx.x * 256 + threadIdx.x;  // 524288 threads
  int hp = gid & 511;            // h-pair, lane-fast
  int chunk = (gid >> 9) & 63;
  int b = gid >> 15;
  const ushort_t* px = U + (size_t)(b * TT + chunk * CLEN) * HH + 2 * hp;
  const ushort_t* pf = px + PLANE;
  float c0 = 0.f, c1 = 0.f, A0 = 1.f, A1 = 1.f;
#pragma unroll
  for (int t = 0; t < CLEN; t++) {
    uint_t xx = *(const uint_t*)(px + (size_t)t * HH);
    uint_t ff = *(const uint_t*)(pf + (size_t)t * HH);
    float x0 = b2f_lo(xx), x1 = b2f_hi(xx);
    float f0 = b2f_lo(ff), f1 = b2f_hi(ff);
    A0 *= f0; c0 = f0 * c0 + (1.f - f0) * x0;
    A1 *= f1; c1 = f1 * c1 + (1.f - f1) * x1;
  }
  // summaries [b][chunk][h] -> lane-coalesced float2
  size_t sidx = ((size_t)(b * NCHUNK + chunk)) * 512 + hp;
  ((float2*)Asum)[sidx] = make_float2(A0, A1);
  ((float2*)Bsum)[sidx] = make_float2(c0, c1);
}

// ---------- kernel 4: sequential combine over chunk summaries ----------
__global__ __launch_bounds__(256) void fixup_kernel(const float* __restrict__ Asum,
                                                    const float* __restrict__ Bsum,
                                                    float* __restrict__ Cinit) {
  int gid = blockIdx.x * 256 + threadIdx.x;  // 16384
  int h = gid & 1023;
  int b = gid >> 10;
  float c = 0.f;
#pragma unroll
  for (int j = 0; j < NCHUNK; j++) {
    size_t idx = ((size_t)(b * NCHUNK + j)) * HH + h;  // coalesced per j
    Cinit[idx] = c;
    c = Bsum[idx] + Asum[idx] * c;
  }
}

// ---------- kernel 5: final scan producing h (out [B,T,H] fp32) ----------
__global__ __launch_bounds__(256) void pass3_kernel(const ushort_t* __restrict__ U,
                                                    const float* __restrict__ Cinit,
                                                    float* __restrict__ out) {
  int gid = blockIdx.x * 256 + threadIdx.x;  // 524288
  int hp = gid & 511;            // h-pair, lane-fast
  int chunk = (gid >> 9) & 63;
  int b = gid >> 15;
  size_t base = (size_t)(b * TT + chunk * CLEN) * HH + 2 * hp;
  const ushort_t* px = U + base;
  const ushort_t* pf = px + PLANE;
  const ushort_t* pr = pf + PLANE;
  float2 ci = ((const float2*)Cinit)[((size_t)(b * NCHUNK + chunk)) * 512 + hp];
  float c0 = ci.x, c1 = ci.y;
  float2* o = (float2*)out + ((size_t)(b * TT + chunk * CLEN)) * 512 + hp;
#pragma unroll
  for (int t = 0; t < CLEN; t++) {
    uint_t xx = *(const uint_t*)(px + (size_t)t * HH);
    uint_t ff = *(const uint_t*)(pf + (size_t)t * HH);
    uint_t rr = *(const uint_t*)(pr + (size_t)t * HH);
    float x0 = b2f_lo(xx), x1 = b2f_hi(xx);
    float f0 = b2f_lo(ff), f1 = b2f_hi(ff);
    float r0 = b2f_lo(rr), r1 = b2f_hi(rr);
    c0 = f0 * c0 + (1.f - f0) * x0;
    c1 = f1 * c1 + (1.f - f1) * x1;
    float h0 = r0 * fast_tanh(c0) + (1.f - r0) * x0;
    float h1 = r1 * fast_tanh(c1) + (1.f - r1) * x1;
    o[(size_t)t * 512] = make_float2(h0, h1);
  }
}

extern "C" void kernel_launch(void* const* d_in, const int* in_sizes, int n_in,
                              void* d_out, int out_size, void* d_ws, size_t ws_size,
                              hipStream_t stream) {
  (void)in_sizes; (void)n_in; (void)out_size; (void)ws_size;
  const float* x = (const float*)d_in[0];
  const float* W = (const float*)d_in[1];
  const float* bias = (const float*)d_in[2];
  float* out = (float*)d_out;
  char* ws = (char*)d_ws;

  // workspace layout (262 MB peak):
  //   x_bf [0, 64MB)            -- dead after gemm
  //   Wt   [64MB, 70MB)
  //   U    [70MB, 262MB)
  //   Asum/Bsum/Cinit alias the dead x_bf region (3 x 4MB)
  ushort_t* x_bf = (ushort_t*)ws;                       // 67,108,864 B
  ushort_t* Wt   = (ushort_t*)(ws + 67108864ull);       //  6,291,456 B
  ushort_t* U    = (ushort_t*)(ws + 73400320ull);       // 201,326,592 B
  float* Asum  = (float*)(ws + 0ull);                   //  4,194,304 B (aliases x_bf)
  float* Bsum  = (float*)(ws + 4194304ull);             //  4,194,304 B
  float* Cinit = (float*)(ws + 8388608ull);             //  4,194,304 B

  cvt_x_kernel<<<1024, 256, 0, stream>>>((const float4*)x, (ushort4*)x_bf, MM * KK / 4);
  transW_kernel<<<dim3(NN / 32, KK / 32), dim3(32, 8), 0, stream>>>(W, Wt);
  gemm_kernel<<<dim3(NN / 128, MM / 128), 256, 0, stream>>>(x_bf, Wt, bias, U);
  pass1_kernel<<<2048, 256, 0, stream>>>(U, Asum, Bsum);
  fixup_kernel<<<64, 256, 0, stream>>>(Asum, Bsum, Cinit);
  pass3_kernel<<<2048, 256, 0, stream>>>(U, Cinit, out);
}